// Round 4
// baseline (408.998 us; speedup 1.0000x reference)
//
#include <hip/hip_runtime.h>
#include <hip/hip_bf16.h>
#include <math.h>

// Problem constants (Qwen2MoeAttention, T=2048)
#define TSEQ   2048
#define HID    2048
#define NH     16
#define NKV    4
#define HD     128
#define KVD    512
#define SCALING 0.08838834764831845f   // 1/sqrt(128)
#define LOG2_ROPE_BASE 19.931568569324174f  // log2(1e6)
#define LOG2E  1.4426950408889634f

typedef float f4  __attribute__((ext_vector_type(4),  aligned(16)));
typedef float f16v __attribute__((ext_vector_type(16), aligned(64)));
typedef short s8v __attribute__((ext_vector_type(8),  aligned(16)));
typedef short s4v __attribute__((ext_vector_type(4),  aligned(8)));

__device__ __forceinline__ short f2bf(float x) {
    union { __hip_bfloat16 b; short s; } u;
    u.b = __float2bfloat16(x);
    return u.s;
}
__device__ __forceinline__ unsigned pk2(float a, float b) {
    return ((unsigned)(unsigned short)f2bf(b) << 16) | (unsigned)(unsigned short)f2bf(a);
}

// ---------------------------------------------------------------------------
// f32 -> bf16 bulk convert (hidden_states), 8 elems/thread
// ---------------------------------------------------------------------------
__global__ __launch_bounds__(256) void f32_to_bf16(
    const float* __restrict__ in, short* __restrict__ out)
{
    const int i = (blockIdx.x * 256 + threadIdx.x) * 8;
    f4 a = *(const f4*)(in + i);
    f4 b = *(const f4*)(in + i + 4);
    s8v v;
    v[0] = f2bf(a[0]); v[1] = f2bf(a[1]); v[2] = f2bf(a[2]); v[3] = f2bf(a[3]);
    v[4] = f2bf(b[0]); v[5] = f2bf(b[1]); v[6] = f2bf(b[2]); v[7] = f2bf(b[3]);
    *(s8v*)(out + i) = v;
}

// ---------------------------------------------------------------------------
// MFMA GPTQ GEMM (16x16x32). MODE 0: f32 row-major out. MODE 1: bf16
// transposed out (Vt[col][T] for attention's V^T operand).
// ---------------------------------------------------------------------------
template<int BM, int BN, int MODE>
__global__ __launch_bounds__(256) void gemm_gptq_mfma(
    const short* __restrict__ X, const int* __restrict__ qw,
    const float* __restrict__ scales, const int* __restrict__ zeros,
    void* __restrict__ Yv, int OUT)
{
    constexpr int WM = BM / 2, WN = BN / 2, FM = WM / 16, FN = WN / 16;
    __shared__ __align__(16) short As[BM * 64];
    __shared__ __align__(16) short Bs[BN * 64];
    const int tid = threadIdx.x;
    const int l = tid & 63, w = tid >> 6;
    const int l15 = l & 15, l4 = l >> 4;
    const int wr = w >> 1, wc = w & 1;
    const int br = blockIdx.y, bc = blockIdx.x;

    const int colB = tid % BN;
    const int colg = bc * BN + colB;
    const int prb  = (tid / BN) * (BN / 32);

    f4 acc[FM][FN] = {};

    for (int kt = 0; kt < 32; ++kt) {
        __syncthreads();
        #pragma unroll
        for (int n = 0; n < BM / 32; ++n) {
            int f = tid + 256 * n;
            int r = f >> 3, c8 = f & 7;
            s8v av = *(const s8v*)(X + (size_t)(br * BM + r) * 2048 + kt * 64 + c8 * 8);
            *(s8v*)(&As[r * 64 + ((c8 * 8) ^ ((r & 7) << 3))]) = av;
        }
        {
            const int g = kt >> 1;
            const float sc = scales[g * OUT + colg];
            const float zf = (float)zeros[g * OUT + colg];
            #pragma unroll
            for (int n = 0; n < BN / 32; ++n) {
                int pr = prb + n;
                unsigned p = (unsigned)qw[(kt * 8 + pr) * OUT + colg];
                s8v bv;
                #pragma unroll
                for (int s = 0; s < 8; ++s) {
                    float qv = (float)((p >> (4 * s)) & 15u);
                    bv[s] = f2bf((qv - zf) * sc);
                }
                *(s8v*)(&Bs[colB * 64 + ((pr * 8) ^ ((colB & 7) << 3))]) = bv;
            }
        }
        __syncthreads();
        #pragma unroll
        for (int ks = 0; ks < 2; ++ks) {
            s8v a[FM], b[FN];
            #pragma unroll
            for (int m_ = 0; m_ < FM; ++m_) {
                int row = wr * WM + m_ * 16 + l15;
                a[m_] = *(const s8v*)(&As[row * 64 + ((ks * 32 + l4 * 8) ^ ((row & 7) << 3))]);
            }
            #pragma unroll
            for (int n_ = 0; n_ < FN; ++n_) {
                int col = wc * WN + n_ * 16 + l15;
                b[n_] = *(const s8v*)(&Bs[col * 64 + ((ks * 32 + l4 * 8) ^ ((col & 7) << 3))]);
            }
            #pragma unroll
            for (int m_ = 0; m_ < FM; ++m_)
                #pragma unroll
                for (int n_ = 0; n_ < FN; ++n_)
                    acc[m_][n_] = __builtin_amdgcn_mfma_f32_16x16x32_bf16(
                        a[m_], b[n_], acc[m_][n_], 0, 0, 0);
        }
    }
    if constexpr (MODE == 0) {
        float* Y = (float*)Yv;
        #pragma unroll
        for (int m_ = 0; m_ < FM; ++m_)
            #pragma unroll
            for (int n_ = 0; n_ < FN; ++n_)
                #pragma unroll
                for (int r = 0; r < 4; ++r)
                    Y[(size_t)(br * BM + wr * WM + m_ * 16 + l4 * 4 + r) * OUT
                      + bc * BN + wc * WN + n_ * 16 + l15] = acc[m_][n_][r];
    } else {
        short* Vt = (short*)Yv;   // [OUT][TSEQ] bf16
        #pragma unroll
        for (int m_ = 0; m_ < FM; ++m_)
            #pragma unroll
            for (int n_ = 0; n_ < FN; ++n_) {
                int col  = bc * BN + wc * WN + n_ * 16 + l15;
                int row0 = br * BM + wr * WM + m_ * 16 + l4 * 4;
                s4v pk;
                #pragma unroll
                for (int r = 0; r < 4; ++r) pk[r] = f2bf(acc[m_][n_][r]);
                *(s4v*)(&Vt[(size_t)col * TSEQ + row0]) = pk;
            }
    }
}

// ---------------------------------------------------------------------------
// RoPE (NeoX): reads f32 q,k; writes bf16 Qg (pre-scaled by SCALING*LOG2E)
// and bf16 Kg.
// ---------------------------------------------------------------------------
__global__ __launch_bounds__(256) void rope_bf16(
    const int* __restrict__ pos, const float* __restrict__ qf,
    const float* __restrict__ kf, short* __restrict__ Qg, short* __restrict__ Kg)
{
    const int t = blockIdx.x;
    const int tid = threadIdx.x;
    const int j = tid & 63;
    const int g = tid >> 6;
    const float p = (float)pos[t];
    const float inv = exp2f(-(float)j * (LOG2_ROPE_BASE / 64.0f));
    const float fr = p * inv;
    float s, c;
    sincosf(fr, &s, &c);
    const float QS = SCALING * LOG2E;
    #pragma unroll
    for (int n = 0; n < 4; ++n) {
        int h = g * 4 + n;
        const float* base = qf + (size_t)t * 2048 + h * 128;
        float x1 = base[j], x2 = base[j + 64];
        Qg[(size_t)t * 2048 + h * 128 + j]      = f2bf((x1 * c - x2 * s) * QS);
        Qg[(size_t)t * 2048 + h * 128 + j + 64] = f2bf((x2 * c + x1 * s) * QS);
    }
    {
        int h = g;
        const float* base = kf + (size_t)t * 512 + h * 128;
        float x1 = base[j], x2 = base[j + 64];
        Kg[(size_t)t * 512 + h * 128 + j]      = f2bf(x1 * c - x2 * s);
        Kg[(size_t)t * 512 + h * 128 + j + 64] = f2bf(x2 * c + x1 * s);
    }
}

// ---------------------------------------------------------------------------
// Swapped-operand 32x32 MFMA flash attention.
// Block = 4 waves = 4 q-heads of one GQA group, sharing K/Vt LDS staging.
// Wave: 32 q-rows. mfma(A=K,B=Q) -> S with q=lane&31 (lane-local softmax);
// mfma(A=Vt,B=P^T) -> O^T with q=lane&31 (scalar rescale).
// D layout (32x32): col=lane&31, row=(reg&3)+8*(reg>>2)+4*(lane>>5).
// A/B: row|col=lane&31, k=(lane>>5)*8+j. LDS XOR-swizzled in 16B units.
// ---------------------------------------------------------------------------
__global__ __launch_bounds__(256, 1) void attn32(
    const short* __restrict__ Qg, const short* __restrict__ Kg,
    const short* __restrict__ Vtg, short* __restrict__ out)
{
    __shared__ __align__(16) short Ks[64 * 128];   // [krow][d], swizzled
    __shared__ __align__(16) short Vs[128 * 64];   // [d][krow], swizzled

    const int tid = threadIdx.x;
    const int l = tid & 63, w = tid >> 6;
    const int h = l >> 5, q = l & 31;
    const int jt = blockIdx.x;            // q-tile (32 rows)
    const int kvh = blockIdx.y;
    const int q0 = jt * 32;
    const int head = kvh * 4 + w;

    // persistent Q fragments (B-operand): k=d-slice, col=q
    s8v qf[8];
    {
        const short* qp = Qg + (size_t)(q0 + q) * 2048 + head * 128 + h * 8;
        #pragma unroll
        for (int d8 = 0; d8 < 8; ++d8) qf[d8] = *(const s8v*)(qp + d8 * 16);
    }

    f16v O[4];
    #pragma unroll
    for (int dt = 0; dt < 4; ++dt)
        #pragma unroll
        for (int r = 0; r < 16; ++r) O[dt][r] = 0.0f;
    float m = -1e30f, lsum = 0.0f;

    const int nch = (jt >> 1) + 1;
    for (int kc = 0; kc < nch; ++kc) {
        const int k0 = kc * 64;
        __syncthreads();
        // --- stage K [64][128] bf16, unit-swizzled ---
        #pragma unroll
        for (int n = 0; n < 4; ++n) {
            int f = tid + 256 * n;
            int r = f >> 4, u = f & 15;
            s8v kv_ = *(const s8v*)(Kg + (size_t)(k0 + r) * 512 + kvh * 128 + u * 8);
            *(s8v*)(&Ks[(r * 16 + (u ^ (r & 7))) * 8]) = kv_;
        }
        // --- stage Vt [128][64] bf16, unit-swizzled ---
        #pragma unroll
        for (int n = 0; n < 4; ++n) {
            int f = tid + 256 * n;
            int d = f >> 3, u = f & 7;
            s8v vv = *(const s8v*)(Vtg + (size_t)(kvh * 128 + d) * TSEQ + k0 + u * 8);
            *(s8v*)(&Vs[(d * 8 + (u ^ (d & 7))) * 8]) = vv;
        }
        __syncthreads();

        // --- QK^T swapped: pD[t] = S[k-tile t][q] ---
        f16v pD[2];
        #pragma unroll
        for (int t = 0; t < 2; ++t)
            #pragma unroll
            for (int r = 0; r < 16; ++r) pD[t][r] = 0.0f;
        #pragma unroll
        for (int t = 0; t < 2; ++t) {
            #pragma unroll
            for (int d8 = 0; d8 < 8; ++d8) {
                int r = t * 32 + q;
                s8v kf = *(const s8v*)(&Ks[(r * 16 + ((d8 * 2 + h) ^ (r & 7))) * 8]);
                pD[t] = __builtin_amdgcn_mfma_f32_32x32x16_bf16(kf, qf[d8], pD[t], 0, 0, 0);
            }
        }
        // --- causal mask (last chunk only; positions are arange) ---
        if (kc == nch - 1) {
            #pragma unroll
            for (int t = 0; t < 2; ++t)
                #pragma unroll
                for (int r = 0; r < 16; ++r) {
                    int koff = (r & 3) + 8 * (r >> 2) + 4 * h + 32 * t;
                    if (k0 + koff > q0 + q) pD[t][r] = -1e30f;
                }
        }
        // --- row max (lane-local + one cross-half shfl) ---
        float mx = pD[0][0];
        #pragma unroll
        for (int r = 1; r < 16; ++r) mx = fmaxf(mx, pD[0][r]);
        #pragma unroll
        for (int r = 0; r < 16; ++r) mx = fmaxf(mx, pD[1][r]);
        mx = fmaxf(mx, __shfl_xor(mx, 32, 64));
        const float mn = fmaxf(m, mx);
        const float sc = exp2f(m - mn);   // S already in log2 domain (Q pre-scaled)
        // --- P = exp2(S - m), row sum ---
        float rs = 0.0f;
        #pragma unroll
        for (int t = 0; t < 2; ++t)
            #pragma unroll
            for (int r = 0; r < 16; ++r) {
                float pv = exp2f(pD[t][r] - mn);
                pD[t][r] = pv;
                rs += pv;
            }
        rs += __shfl_xor(rs, 32, 64);
        lsum = lsum * sc + rs;
        m = mn;
        // --- rescale O (scalar per lane) ---
        #pragma unroll
        for (int dt = 0; dt < 4; ++dt)
            #pragma unroll
            for (int r = 0; r < 16; ++r) O[dt][r] *= sc;
        // --- pack P -> bf16 B-fragments (exchange quads with lane^32) ---
        s8v pf[4];
        #pragma unroll
        for (int s = 0; s < 4; ++s) {
            const int t = s >> 1, c = s & 1;
            const int bk = 8 * c + 4 * h;        // own (keep) quad
            const int bs = 8 * c + 4 * (1 - h);  // send quad
            unsigned kp0 = pk2(pD[t][bk + 0], pD[t][bk + 1]);
            unsigned kp1 = pk2(pD[t][bk + 2], pD[t][bk + 3]);
            unsigned sp0 = pk2(pD[t][bs + 0], pD[t][bs + 1]);
            unsigned sp1 = pk2(pD[t][bs + 2], pD[t][bs + 3]);
            unsigned r0 = __shfl_xor((int)sp0, 32, 64);
            unsigned r1 = __shfl_xor((int)sp1, 32, 64);
            union { unsigned u[4]; s8v v; } fr;
            fr.u[0] = h ? r0 : kp0;
            fr.u[1] = h ? r1 : kp1;
            fr.u[2] = h ? kp0 : r0;
            fr.u[3] = h ? kp1 : r1;
            pf[s] = fr.v;
        }
        // --- PV swapped: O^T[dt] += Vt-frag * P^T-frag ---
        #pragma unroll
        for (int s = 0; s < 4; ++s) {
            #pragma unroll
            for (int dt = 0; dt < 4; ++dt) {
                int r = dt * 32 + q;
                s8v vf = *(const s8v*)(&Vs[(r * 8 + ((2 * s + h) ^ (r & 7))) * 8]);
                O[dt] = __builtin_amdgcn_mfma_f32_32x32x16_bf16(vf, pf[s], O[dt], 0, 0, 0);
            }
        }
    }

    // --- epilogue: out[q][head*128 + d] = O/l (bf16) ---
    const float il = 1.0f / lsum;
    #pragma unroll
    for (int dt = 0; dt < 4; ++dt)
        #pragma unroll
        for (int g2 = 0; g2 < 4; ++g2) {
            int d4 = dt * 32 + 8 * g2 + 4 * h;
            s4v ov;
            #pragma unroll
            for (int r = 0; r < 4; ++r) ov[r] = f2bf(O[dt][g2 * 4 + r] * il);
            *(s4v*)(out + (size_t)(q0 + q) * 2048 + head * 128 + d4) = ov;
        }
}

// ---------------------------------------------------------------------------
extern "C" void kernel_launch(void* const* d_in, const int* in_sizes, int n_in,
                              void* d_out, int out_size, void* d_ws, size_t ws_size,
                              hipStream_t stream)
{
    const int*   positions = (const int*)  d_in[0];
    const float* hidden    = (const float*)d_in[1];
    const int*   q_qw = (const int*)  d_in[2];
    const float* q_sc = (const float*)d_in[3];
    const int*   q_zr = (const int*)  d_in[4];
    const int*   k_qw = (const int*)  d_in[5];
    const float* k_sc = (const float*)d_in[6];
    const int*   k_zr = (const int*)  d_in[7];
    const int*   v_qw = (const int*)  d_in[8];
    const float* v_sc = (const float*)d_in[9];
    const int*   v_zr = (const int*)  d_in[10];
    const int*   o_qw = (const int*)  d_in[11];
    const float* o_sc = (const float*)d_in[12];
    const int*   o_zr = (const int*)  d_in[13];
    float* outf = (float*)d_out;

    // workspace (32 MB), with lifetime-based aliasing:
    //  [0,16M):  qbuf f32[T,2048]   -> later abuf bf16[T,2048] (attn out)
    //  [16M,20M): kbuf f32[T,512]
    //  [20M,28M): hb bf16[2048,2048] -> later Qg bf16[T,2048] (rope out)
    //  [28M,30M): Kg bf16[T,512]
    //  [30M,32M): Vtg bf16[512,T]
    char* base = (char*)d_ws;
    float* qbuf = (float*)(base);
    short* abuf = (short*)(base);
    float* kbuf = (float*)(base + (16u << 20));
    short* hb   = (short*)(base + (20u << 20));
    short* Qg   = (short*)(base + (20u << 20));
    short* Kg   = (short*)(base + (28u << 20));
    short* Vtg  = (short*)(base + (30u << 20));

    dim3 blk(256);
    f32_to_bf16<<<dim3(2048), blk, 0, stream>>>(hidden, hb);
    gemm_gptq_mfma<128, 64, 0><<<dim3(32, 16), blk, 0, stream>>>(hb, q_qw, q_sc, q_zr, qbuf, 2048);
    gemm_gptq_mfma<64, 64, 0><<<dim3(8, 32), blk, 0, stream>>>(hb, k_qw, k_sc, k_zr, kbuf, 512);
    gemm_gptq_mfma<64, 64, 1><<<dim3(8, 32), blk, 0, stream>>>(hb, v_qw, v_sc, v_zr, (void*)Vtg, 512);
    rope_bf16<<<dim3(TSEQ), blk, 0, stream>>>(positions, qbuf, kbuf, Qg, Kg);
    attn32<<<dim3(TSEQ / 32, NKV), blk, 0, stream>>>(Qg, Kg, Vtg, abuf);
    gemm_gptq_mfma<128, 64, 0><<<dim3(32, 16), blk, 0, stream>>>(abuf, o_qw, o_sc, o_zr, outf, 2048);
}